// Round 3
// baseline (1549.332 us; speedup 1.0000x reference)
//
#include <hip/hip_runtime.h>
#include <hip/hip_bf16.h>
#include <math.h>

#define BB 16
#define TT 4096
#define HH 1024
#define SS 16
#define PP 6
#define NHH 8
#define DHH 128
#define NLL 2

typedef __hip_bfloat16 bf16;

__device__ __forceinline__ float b2f(bf16 x){ return __bfloat162float(x); }
__device__ __forceinline__ float us2f(unsigned short u){ return __uint_as_float(((unsigned)u) << 16); }

template<int ISBF>
__device__ __forceinline__ float ldw(const void* p, size_t i){
    if (ISBF) return b2f(((const bf16*)p)[i]);
    else      return ((const float*)p)[i];
}

// ---------------- init: zero scalars + detect input dtype ----------------
// ln_g is all-ones: first 32-bit word is 0x3F800000 (fp32) or 0x3F803F80 (bf16 pair).
__global__ void k_init(const unsigned* __restrict__ lng, float* __restrict__ scal,
                       int* __restrict__ flag){
    if (threadIdx.x == 0){
        scal[0] = 0.f; scal[1] = 0.f; scal[2] = 0.f; scal[3] = 0.f;
        flag[0] = (lng[0] == 0x3F800000u) ? 0 : 1;
    }
}

// ---------------- lengths ----------------
__global__ void k_len(const int* __restrict__ mask, int* __restrict__ L){
    int b = blockIdx.x, tid = threadIdx.x;
    int s = 0;
    for (int t = tid; t < TT; t += 256) s += mask[b*TT + t];
    __shared__ int red[256];
    red[tid] = s; __syncthreads();
    for (int w = 128; w > 0; w >>= 1){ if (tid < w) red[tid] += red[tid+w]; __syncthreads(); }
    if (tid == 0) L[b] = red[0];
}

// ---------------- segment mean pool ----------------
template<int ISBF>
__device__ void segpool_body(const void* __restrict__ tok, const int* __restrict__ L,
                             float* __restrict__ seg){
    int s = blockIdx.x, b = blockIdx.y;
    int len = L[b];
    int lo = (s*len)/SS, hi = ((s+1)*len)/SS;
    int tid = threadIdx.x;
    int h0 = tid*4;
    float a0=0.f,a1=0.f,a2=0.f,a3=0.f;
    if (ISBF){
        const bf16* t = (const bf16*)tok;
        for (int tt = lo; tt < hi; ++tt){
            ushort4 u = *(const ushort4*)(t + ((size_t)(b*TT + tt))*HH + h0);
            a0 += us2f(u.x); a1 += us2f(u.y); a2 += us2f(u.z); a3 += us2f(u.w);
        }
    } else {
        const float* t = (const float*)tok;
        for (int tt = lo; tt < hi; ++tt){
            float4 u = *(const float4*)(t + ((size_t)(b*TT + tt))*HH + h0);
            a0 += u.x; a1 += u.y; a2 += u.z; a3 += u.w;
        }
    }
    float inv = 1.0f/(float)(hi-lo);
    float* o = seg + ((size_t)(b*SS + s))*HH + h0;
    o[0]=a0*inv; o[1]=a1*inv; o[2]=a2*inv; o[3]=a3*inv;
}
__global__ void k_segpool(const void* __restrict__ tok, const int* __restrict__ L,
                          float* __restrict__ seg, const int* __restrict__ flag){
    if (*flag) segpool_body<1>(tok, L, seg); else segpool_body<0>(tok, L, seg);
}

// ------- generic Y = act(X @ W[offW..]^T + bias[offB..]) (+R), fp32 in/out -------
template<int ISBF, int ACT, int RES>
__device__ void gemm_body(const float* __restrict__ X, const void* __restrict__ W,
                          const void* __restrict__ bias, const float* __restrict__ R,
                          float* __restrict__ Y, int N, int K, int M,
                          size_t offW, int offB){
    __shared__ float Xs[16][17], Ws[16][17];
    int tx = threadIdx.x, ty = threadIdx.y;
    int row = blockIdx.y*16 + ty;
    int col = blockIdx.x*16 + tx;
    float acc = 0.f;
    for (int k0 = 0; k0 < K; k0 += 16){
        Xs[ty][tx] = (row < N) ? X[(size_t)row*K + k0 + tx] : 0.f;
        Ws[ty][tx] = ldw<ISBF>(W, offW + (size_t)(blockIdx.x*16 + ty)*K + k0 + tx); // M%16==0
        __syncthreads();
        #pragma unroll
        for (int kk = 0; kk < 16; ++kk) acc += Xs[ty][kk]*Ws[tx][kk];
        __syncthreads();
    }
    if (row < N){
        float v = acc + ldw<ISBF>(bias, (size_t)(offB + col));
        if (ACT == 1) v = 0.5f*v*(1.0f + erff(v*0.70710678118654752f));
        if (RES == 1) v += R[(size_t)row*M + col];
        Y[(size_t)row*M + col] = v;
    }
}
template<int ACT, int RES>
__global__ void k_gemm(const float* __restrict__ X, const void* __restrict__ W,
                       const void* __restrict__ bias, const float* __restrict__ R,
                       float* __restrict__ Y, int N, int K, int M,
                       size_t offW, int offB, const int* __restrict__ flag){
    if (*flag) gemm_body<1,ACT,RES>(X,W,bias,R,Y,N,K,M,offW,offB);
    else       gemm_body<0,ACT,RES>(X,W,bias,R,Y,N,K,M,offW,offB);
}

// ---------------- MHA core (no mask needed: all segments valid) ----------------
__global__ void k_attn(const float* __restrict__ Qb, const float* __restrict__ Kb,
                       const float* __restrict__ Vb, float* __restrict__ O,
                       int nq, int nk, int sQ, int sKV, int qShared){
    __shared__ float Qs[16][DHH], Ks[16][DHH], Vs[16][DHH];
    __shared__ float sc[16][17];
    int b = blockIdx.x / NHH, h = blockIdx.x % NHH;
    int tid = threadIdx.x;
    for (int idx = tid; idx < nq*DHH; idx += 256){
        int i = idx >> 7, d = idx & 127;
        int r = qShared ? i : (b*nq + i);
        Qs[i][d] = Qb[(size_t)r*sQ + h*DHH + d];
    }
    for (int idx = tid; idx < nk*DHH; idx += 256){
        int j = idx >> 7, d = idx & 127;
        Ks[j][d] = Kb[(size_t)(b*nk + j)*sKV + h*DHH + d];
        Vs[j][d] = Vb[(size_t)(b*nk + j)*sKV + h*DHH + d];
    }
    __syncthreads();
    const float scale = 0.0883883476483184406f; // 1/sqrt(128)
    for (int idx = tid; idx < nq*nk; idx += 256){
        int i = idx / nk, j = idx % nk;
        float s = 0.f;
        for (int d = 0; d < DHH; ++d) s += Qs[i][d]*Ks[j][d];
        sc[i][j] = s * scale;
    }
    __syncthreads();
    if (tid < nq){
        float m = -1e30f;
        for (int j = 0; j < nk; ++j) m = fmaxf(m, sc[tid][j]);
        float ssum = 0.f;
        for (int j = 0; j < nk; ++j){ float e = expf(sc[tid][j] - m); sc[tid][j] = e; ssum += e; }
        float inv = 1.0f/ssum;
        for (int j = 0; j < nk; ++j) sc[tid][j] *= inv;
    }
    __syncthreads();
    for (int idx = tid; idx < nq*DHH; idx += 256){
        int i = idx >> 7, d = idx & 127;
        float o = 0.f;
        for (int j = 0; j < nk; ++j) o += sc[i][j]*Vs[j][d];
        O[(size_t)(b*nq + i)*HH + h*DHH + d] = o;
    }
}

// -------- LayerNorm over H=1024, one block/row, g/b at element offset --------
template<int ISBF>
__device__ void ln_body(const float* __restrict__ X, const void* __restrict__ g,
                        const void* __restrict__ bta, float* __restrict__ Y, int off){
    int row = blockIdx.x, tid = threadIdx.x;
    const float* x = X + (size_t)row*HH;
    float v[4]; float s = 0.f, sq = 0.f;
    #pragma unroll
    for (int u = 0; u < 4; ++u){ v[u] = x[tid + u*256]; s += v[u]; sq += v[u]*v[u]; }
    __shared__ float r1[256], r2[256];
    r1[tid] = s; r2[tid] = sq; __syncthreads();
    for (int w = 128; w > 0; w >>= 1){
        if (tid < w){ r1[tid] += r1[tid+w]; r2[tid] += r2[tid+w]; }
        __syncthreads();
    }
    float mean = r1[0]*(1.0f/HH);
    float var  = fmaxf(r2[0]*(1.0f/HH) - mean*mean, 0.f);
    float rstd = rsqrtf(var + 1e-5f);
    float* y = Y + (size_t)row*HH;
    #pragma unroll
    for (int u = 0; u < 4; ++u){
        int c = tid + u*256;
        y[c] = (v[u]-mean)*rstd*ldw<ISBF>(g, (size_t)(off+c)) + ldw<ISBF>(bta, (size_t)(off+c));
    }
}
__global__ void k_ln(const float* __restrict__ X, const void* __restrict__ g,
                     const void* __restrict__ bta, float* __restrict__ Y,
                     int off, const int* __restrict__ flag){
    if (*flag) ln_body<1>(X,g,bta,Y,off); else ln_body<0>(X,g,bta,Y,off);
}

// ---------------- salience logits + softmax + entropy ----------------
template<int ISBF>
__device__ void sal_body(const float* __restrict__ Hbuf, const void* __restrict__ w2,
                         const void* __restrict__ b2v, float* __restrict__ sal,
                         float* __restrict__ scal){
    int b = blockIdx.x, tid = threadIdx.x;
    __shared__ float red[256];
    __shared__ float lg[SS];
    for (int s = 0; s < SS; ++s){
        const float* hr = Hbuf + (size_t)(b*SS + s)*HH;
        float acc = 0.f;
        for (int k = tid; k < HH; k += 256) acc += hr[k]*ldw<ISBF>(w2, (size_t)k);
        red[tid] = acc; __syncthreads();
        for (int w = 128; w > 0; w >>= 1){ if (tid < w) red[tid] += red[tid+w]; __syncthreads(); }
        if (tid == 0) lg[s] = red[0] + ldw<ISBF>(b2v, 0);
        __syncthreads();
    }
    if (tid == 0){
        float m = -1e30f;
        for (int s = 0; s < SS; ++s) m = fmaxf(m, lg[s]);
        float ssum = 0.f;
        for (int s = 0; s < SS; ++s){ float e = expf(lg[s]-m); lg[s] = e; ssum += e; }
        float inv = 1.0f/ssum, ent = 0.f;
        for (int s = 0; s < SS; ++s){
            float p = lg[s]*inv;
            sal[b*SS+s] = p;
            ent -= p*logf(p + 1e-8f);
        }
        atomicAdd(&scal[0], ent);
    }
}
__global__ void k_sal(const float* __restrict__ Hbuf, const void* __restrict__ w2,
                      const void* __restrict__ b2v, float* __restrict__ sal,
                      float* __restrict__ scal, const int* __restrict__ flag){
    if (*flag) sal_body<1>(Hbuf,w2,b2v,sal,scal); else sal_body<0>(Hbuf,w2,b2v,sal,scal);
}

__global__ void k_wseg(const float* __restrict__ seg, const float* __restrict__ sal,
                       float* __restrict__ wseg){
    int i = blockIdx.x*256 + threadIdx.x;
    wseg[i] = seg[i]*sal[i/HH];
}

// convert plan_q (either dtype) to fp32
__global__ void k_cvt(const void* __restrict__ in, float* __restrict__ out, int n,
                      const int* __restrict__ flag){
    int i = blockIdx.x*256 + threadIdx.x;
    if (i < n){
        if (*flag) out[i] = b2f(((const bf16*)in)[i]);
        else       out[i] = ((const float*)in)[i];
    }
}

// ---------------- redundancy ----------------
__global__ void k_red(const float* __restrict__ plan, float* __restrict__ scal){
    int b = blockIdx.x, tid = threadIdx.x;
    __shared__ float Pl[PP][HH];
    __shared__ float red[256];
    __shared__ float nrm[PP];
    for (int idx = tid; idx < PP*HH; idx += 256)
        Pl[idx/HH][idx%HH] = plan[(size_t)b*PP*HH + idx];
    __syncthreads();
    for (int p = 0; p < PP; ++p){
        float a = 0.f;
        for (int k = tid; k < HH; k += 256){ float v = Pl[p][k]; a += v*v; }
        red[tid] = a; __syncthreads();
        for (int w = 128; w > 0; w >>= 1){ if (tid < w) red[tid] += red[tid+w]; __syncthreads(); }
        if (tid == 0) nrm[p] = fmaxf(sqrtf(red[0]), 1e-12f);
        __syncthreads();
    }
    float total = 0.f;
    for (int p = 0; p < PP; ++p){
        for (int q = p+1; q < PP; ++q){
            float a = 0.f;
            for (int k = tid; k < HH; k += 256) a += Pl[p][k]*Pl[q][k];
            red[tid] = a; __syncthreads();
            for (int w = 128; w > 0; w >>= 1){ if (tid < w) red[tid] += red[tid+w]; __syncthreads(); }
            if (tid == 0){ float s = red[0]/(nrm[p]*nrm[q]); total += 2.0f*s*s; }
            __syncthreads();
        }
    }
    if (tid == 0) atomicAdd(&scal[1], total);
}

// ---------------- output assembly (dtype-dispatched store) ----------------
__global__ void k_out(const float* __restrict__ plan, const float* __restrict__ sal,
                      const float* __restrict__ scal, void* __restrict__ outv,
                      const int* __restrict__ flag){
    int i = blockIdx.x*256 + threadIdx.x;
    const int NPLAN = BB*PP*HH;          // 98304
    const int NSAL  = BB*SS;             // 256
    float v;
    if (i < NPLAN) v = plan[i];
    else if (i < NPLAN + NSAL) v = sal[i - NPLAN];
    else if (i == NPLAN + NSAL) v = scal[0] * (1.0f/BB);
    else if (i == NPLAN + NSAL + 1) v = scal[1] * (1.0f/(BB*PP*(PP-1)));
    else return;
    if (*flag) ((bf16*)outv)[i] = __float2bfloat16(v);
    else       ((float*)outv)[i] = v;
}

extern "C" void kernel_launch(void* const* d_in, const int* in_sizes, int n_in,
                              void* d_out, int out_size, void* d_ws, size_t ws_size,
                              hipStream_t stream) {
    const void* tok      = d_in[0];
    const int*  mask     = (const int*)d_in[1];
    const void* sa_in_w  = d_in[2];
    const void* sa_in_b  = d_in[3];
    const void* sa_out_w = d_in[4];
    const void* sa_out_b = d_in[5];
    const void* ln_g     = d_in[6];
    const void* ln_b     = d_in[7];
    const void* sal_w1   = d_in[8];
    const void* sal_b1   = d_in[9];
    const void* sal_w2   = d_in[10];
    const void* sal_b2   = d_in[11];
    const void* plan_q   = d_in[12];
    const void* qa_in_w  = d_in[13];
    const void* qa_in_b  = d_in[14];
    const void* qa_out_w = d_in[15];
    const void* qa_out_b = d_in[16];
    const void* r_in_w   = d_in[17];
    const void* r_in_b   = d_in[18];
    const void* r_out_w  = d_in[19];
    const void* r_out_b  = d_in[20];
    const void* r_ln1_g  = d_in[21];
    const void* r_ln1_b  = d_in[22];
    const void* r_ln2_g  = d_in[23];
    const void* r_ln2_b  = d_in[24];
    const void* r_w1     = d_in[25];
    const void* r_b1     = d_in[26];
    const void* r_w2     = d_in[27];
    const void* r_b2     = d_in[28];

    float* ws   = (float*)d_ws;
    float* seg  = ws;                      // B*S*H
    float* qkv  = seg  + BB*SS*HH;         // B*S*3H
    float* t1   = qkv  + BB*SS*3*HH;       // B*S*H
    float* t2   = t1   + BB*SS*HH;         // B*S*H
    float* plan = t2   + BB*SS*HH;         // B*P*H
    float* ybuf = plan + BB*PP*HH;         // B*P*H
    float* qkv2 = ybuf + BB*PP*HH;         // B*P*4H
    float* pbuf = qkv2 + BB*PP*4*HH;       // B*P*H
    float* sal  = pbuf + BB*PP*HH;         // B*S
    float* qx   = sal  + BB*SS;            // P*H
    float* qh   = qx   + PP*HH;            // P*H
    float* scal = qh   + PP*HH;            // 4
    int*   Lw   = (int*)(scal + 4);        // B
    int*   flag = Lw + BB;                 // 1

    dim3 t16(16,16);
    k_init<<<1, 64, 0, stream>>>((const unsigned*)ln_g, scal, flag);
    k_len<<<BB, 256, 0, stream>>>(mask, Lw);
    k_segpool<<<dim3(SS, BB), 256, 0, stream>>>(tok, Lw, seg, flag);

    // --- self-attention over segments ---
    k_gemm<0,0><<<dim3(3*HH/16, BB*SS/16), t16, 0, stream>>>(seg, sa_in_w, sa_in_b, nullptr, qkv, BB*SS, HH, 3*HH, (size_t)0, 0, flag);
    k_attn<<<BB*NHH, 256, 0, stream>>>(qkv, qkv+HH, qkv+2*HH, t1, SS, SS, 3*HH, 3*HH, 0);
    k_gemm<0,1><<<dim3(HH/16, BB*SS/16), t16, 0, stream>>>(t1, sa_out_w, sa_out_b, seg, t2, BB*SS, HH, HH, (size_t)0, 0, flag);
    k_ln<<<BB*SS, 256, 0, stream>>>(t2, ln_g, ln_b, seg, 0, flag);

    // --- salience ---
    k_gemm<1,0><<<dim3(HH/16, BB*SS/16), t16, 0, stream>>>(seg, sal_w1, sal_b1, nullptr, t1, BB*SS, HH, HH, (size_t)0, 0, flag);
    k_sal<<<BB, 256, 0, stream>>>(t1, sal_w2, sal_b2, sal, scal, flag);
    k_wseg<<<BB*SS*HH/256, 256, 0, stream>>>(seg, sal, t2);   // t2 = wseg

    // --- plan attention (query = plan_q broadcast) ---
    k_cvt<<<(PP*HH+255)/256, 256, 0, stream>>>(plan_q, qx, PP*HH, flag);
    k_gemm<0,0><<<dim3(HH/16, 1), t16, 0, stream>>>(qx, qa_in_w, qa_in_b, nullptr, qh, PP, HH, HH, (size_t)0, 0, flag);
    k_gemm<0,0><<<dim3(2*HH/16, BB*SS/16), t16, 0, stream>>>(t2, qa_in_w, qa_in_b, nullptr, qkv, BB*SS, HH, 2*HH, (size_t)HH*HH, HH, flag);
    k_attn<<<BB*NHH, 256, 0, stream>>>(qh, qkv, qkv+HH, pbuf, PP, SS, HH, 2*HH, 1);
    k_gemm<0,0><<<dim3(HH/16, BB*PP/16), t16, 0, stream>>>(pbuf, qa_out_w, qa_out_b, nullptr, plan, BB*PP, HH, HH, (size_t)0, 0, flag);

    // --- NL transformer encoder layers (norm_first) ---
    for (int l = 0; l < NLL; ++l){
        k_ln<<<BB*PP, 256, 0, stream>>>(plan, r_ln1_g, r_ln1_b, ybuf, l*HH, flag);
        k_gemm<0,0><<<dim3(3*HH/16, BB*PP/16), t16, 0, stream>>>(ybuf, r_in_w, r_in_b, nullptr, qkv2, BB*PP, HH, 3*HH, (size_t)l*3*HH*HH, l*3*HH, flag);
        k_attn<<<BB*NHH, 256, 0, stream>>>(qkv2, qkv2+HH, qkv2+2*HH, pbuf, PP, PP, 3*HH, 3*HH, 0);
        k_gemm<0,1><<<dim3(HH/16, BB*PP/16), t16, 0, stream>>>(pbuf, r_out_w, r_out_b, plan, plan, BB*PP, HH, HH, (size_t)l*HH*HH, l*HH, flag);
        k_ln<<<BB*PP, 256, 0, stream>>>(plan, r_ln2_g, r_ln2_b, ybuf, l*HH, flag);
        k_gemm<1,0><<<dim3(4*HH/16, BB*PP/16), t16, 0, stream>>>(ybuf, r_w1, r_b1, nullptr, qkv2, BB*PP, HH, 4*HH, (size_t)l*4*HH*HH, l*4*HH, flag);
        k_gemm<0,1><<<dim3(HH/16, BB*PP/16), t16, 0, stream>>>(qkv2, r_w2, r_b2, plan, plan, BB*PP, 4*HH, HH, (size_t)l*HH*4*HH, l*HH, flag);
    }

    // --- scalars + output assembly ---
    k_red<<<BB, 256, 0, stream>>>(plan, scal);
    k_out<<<(BB*PP*HH + BB*SS + 2 + 255)/256, 256, 0, stream>>>(plan, sal, scal, d_out, flag);
}